// Round 5
// baseline (2685.386 us; speedup 1.0000x reference)
//
#include <hip/hip_runtime.h>

#define N_NODES 100000
#define N_EDGES 1600000
#define F_IN 512
#define F_HID 128
#define F_OUT 64

__device__ float gcnx5_bf2f(unsigned short u) {
    return __uint_as_float(((unsigned int)u) << 16);
}

__device__ unsigned short gcnx5_f2bf(float f) {
    unsigned int u = __float_as_uint(f);
    u = u + 0x7fffu + ((u >> 16) & 1u);
    return (unsigned short)(u >> 16);
}

__global__ void GCN_16716012716713_kernel() {}

__global__ void gcnx5_zero(float* p, int n) {
    int i = blockIdx.x * blockDim.x + threadIdx.x;
    if (i < n) p[i] = 0.0f;
}

// edge_index dtype probe: int64 data has zero high words (odd int32 slots) in
// the first 1024 elements; int32 data has random node ids there. 1=int32 0=int64
__global__ void gcnx5_iprobe(const int* raw, int* iflag) {
    if (blockIdx.x == 0 && threadIdx.x == 0) {
        int f = 0;
        for (int i = 0; i < 1024; i = i + 1) {
            if (raw[2 * i + 1] != 0) f = 1;
        }
        iflag[0] = f;
    }
}

// float dtype probe on x (values ~ N(0,1)): for bf16-pair data the low u16 of
// each u32 is a bf16 with exponent field in [110,140] almost surely; for fp32
// data it is uniform mantissa bits (~12% in range). 1=bf16 0=fp32
__global__ void gcnx5_fprobe(const unsigned int* xw, int* fflag) {
    if (blockIdx.x == 0 && threadIdx.x == 0) {
        int cnt = 0;
        for (int i = 0; i < 4096; i = i + 1) {
            unsigned int lo = xw[i] & 0xffffu;
            unsigned int e = (lo >> 7) & 0xffu;
            if (e >= 110u && e <= 140u) cnt = cnt + 1;
        }
        fflag[0] = (cnt > 2048) ? 1 : 0;
    }
}

// normalize edge_index to packed int32[2*E]
__global__ void gcnx5_pack(const int* raw, const int* iflag, int* ei) {
    int i = blockIdx.x * blockDim.x + threadIdx.x;
    if (i < 2 * N_EDGES) {
        if (iflag[0] == 0) {
            ei[i] = raw[2 * i];
        } else {
            ei[i] = raw[i];
        }
    }
}

// convert a small float tensor (bf16 or fp32 per flag) to fp32
__global__ void gcnx5_cvt(const void* src, const int* fflag, float* dst, int n) {
    int i = blockIdx.x * blockDim.x + threadIdx.x;
    if (i < n) {
        if (fflag[0] == 1) {
            dst[i] = gcnx5_bf2f(((const unsigned short*)src)[i]);
        } else {
            dst[i] = ((const float*)src)[i];
        }
    }
}

__global__ void gcnx5_deg(const int* ei, int* deg) {
    int e = blockIdx.x * blockDim.x + threadIdx.x;
    if (e < N_EDGES) {
        atomicAdd(&deg[ei[N_EDGES + e]], 1);
    }
}

__global__ void gcnx5_dinv(const int* deg, float* dinv) {
    int i = blockIdx.x * blockDim.x + threadIdx.x;
    if (i < N_NODES) {
        dinv[i] = rsqrtf((float)deg[i] + 1.0f);
    }
}

// h1[m, 0:128] = x[m, 0:512] @ W1f ; one block (128 threads) per row m
__global__ void gcnx5_gemm1(const void* x, const int* fflag, const float* W,
                            float* h1) {
    __shared__ float xs[F_IN];
    int m = blockIdx.x;
    int tid = threadIdx.x;
    int isbf = fflag[0];
    for (int i = tid; i < F_IN; i = i + 128) {
        long long idx = (long long)m * F_IN + i;
        if (isbf == 1) {
            xs[i] = gcnx5_bf2f(((const unsigned short*)x)[idx]);
        } else {
            xs[i] = ((const float*)x)[idx];
        }
    }
    __syncthreads();
    float acc = 0.0f;
    for (int k = 0; k < F_IN; k = k + 1) {
        acc = acc + xs[k] * W[k * F_HID + tid];
    }
    h1[(long long)m * F_HID + tid] = acc;
}

// agg1[d, f] += h1[s, f] * dinv[s] * dinv[d] ; one thread per (edge, feature)
__global__ void gcnx5_agg1(const int* ei, const float* dinv, const float* h1,
                           float* agg1) {
    long long t = (long long)blockIdx.x * blockDim.x + threadIdx.x;
    if (t < (long long)N_EDGES * F_HID) {
        int e = (int)(t >> 7);
        int f = (int)(t & 127);
        int s = ei[e];
        int d = ei[N_EDGES + e];
        float v = h1[(long long)s * F_HID + f] * dinv[s] * dinv[d];
        atomicAdd(&agg1[(long long)d * F_HID + f], v);
    }
}

// r1 = relu(agg1 + h1*dinv^2 + b1); h2[m, 0:64] = r1 @ W2f ; one block (64 thr) per row
__global__ void gcnx5_gemm2(const float* agg1, const float* h1, const float* dinv,
                            const float* b1, const float* W2, float* h2) {
    __shared__ float rs[F_HID];
    int m = blockIdx.x;
    int tid = threadIdx.x;
    float s2 = dinv[m] * dinv[m];
    for (int i = tid; i < F_HID; i = i + 64) {
        long long idx = (long long)m * F_HID + i;
        float v = agg1[idx] + h1[idx] * s2 + b1[i];
        if (v < 0.0f) v = 0.0f;
        rs[i] = v;
    }
    __syncthreads();
    float acc = 0.0f;
    for (int k = 0; k < F_HID; k = k + 1) {
        acc = acc + rs[k] * W2[k * F_OUT + tid];
    }
    h2[(long long)m * F_OUT + tid] = acc;
}

// agg2[d, f] += h2[s, f] * dinv[s] * dinv[d]
__global__ void gcnx5_agg2(const int* ei, const float* dinv, const float* h2,
                           float* agg2) {
    long long t = (long long)blockIdx.x * blockDim.x + threadIdx.x;
    if (t < (long long)N_EDGES * F_OUT) {
        int e = (int)(t >> 6);
        int f = (int)(t & 63);
        int s = ei[e];
        int d = ei[N_EDGES + e];
        float v = h2[(long long)s * F_OUT + f] * dinv[s] * dinv[d];
        atomicAdd(&agg2[(long long)d * F_OUT + f], v);
    }
}

// out = (agg2 + h2*dinv^2 + b2), stored in the same float format as the inputs
__global__ void gcnx5_final(const float* agg2, const float* h2, const float* dinv,
                            const float* b2, const int* fflag, void* out) {
    int idx = blockIdx.x * blockDim.x + threadIdx.x;
    if (idx < N_NODES * F_OUT) {
        int m = idx >> 6;
        int n = idx & 63;
        float s2 = dinv[m] * dinv[m];
        float v = agg2[idx] + h2[idx] * s2 + b2[n];
        if (fflag[0] == 1) {
            ((unsigned short*)out)[idx] = gcnx5_f2bf(v);
        } else {
            ((float*)out)[idx] = v;
        }
    }
}

extern "C" void kernel_launch(void* const* d_in, const int* in_sizes, int n_in,
                              void* d_out, int out_size, void* d_ws, size_t ws_size,
                              hipStream_t stream) {
    const void* x     = d_in[0];
    const int* ei_raw = (const int*)d_in[1];
    const void* W1    = d_in[2];
    const void* b1    = d_in[3];
    const void* W2    = d_in[4];
    const void* b2    = d_in[5];

    // workspace layout (byte offsets, 16B-aligned), end ~164.4 MB (same as round 4):
    char* ws = (char*)d_ws;
    int*   deg   = (int*)(ws + 0);            //    400,000 B
    int*   iflag = (int*)(ws + 409600);       //          4 B
    int*   fflag = (int*)(ws + 409616);       //          4 B
    float* dinv  = (float*)(ws + 524288);     //    400,000 B
    float* W1f   = (float*)(ws + 1048576);    //    262,144 B
    float* b1f   = (float*)(ws + 1310720);    //        512 B
    float* W2f   = (float*)(ws + 1311232);    //     32,768 B
    float* b2f   = (float*)(ws + 1344000);    //        256 B
    int*   ei    = (int*)(ws + 2097152);      // 12,800,000 B
    float* h1    = (float*)(ws + 16777216);   // 51,200,000 B
    float* agg1  = (float*)(ws + 68157440);   // 51,200,000 B
    float* h2    = (float*)(ws + 119537664);  // 25,600,000 B
    float* agg2  = (float*)(ws + 146800640);  // 25,600,000 B

    gcnx5_zero<<<(N_NODES + 255) / 256, 256, 0, stream>>>((float*)deg, N_NODES);
    gcnx5_zero<<<(N_NODES * F_HID + 255) / 256, 256, 0, stream>>>(agg1, N_NODES * F_HID);
    gcnx5_zero<<<(N_NODES * F_OUT + 255) / 256, 256, 0, stream>>>(agg2, N_NODES * F_OUT);

    gcnx5_iprobe<<<1, 64, 0, stream>>>(ei_raw, iflag);
    gcnx5_fprobe<<<1, 64, 0, stream>>>((const unsigned int*)x, fflag);

    gcnx5_pack<<<(2 * N_EDGES + 255) / 256, 256, 0, stream>>>(ei_raw, iflag, ei);

    gcnx5_cvt<<<(F_IN * F_HID + 255) / 256, 256, 0, stream>>>(W1, fflag, W1f, F_IN * F_HID);
    gcnx5_cvt<<<1, 128, 0, stream>>>(b1, fflag, b1f, F_HID);
    gcnx5_cvt<<<(F_HID * F_OUT + 255) / 256, 256, 0, stream>>>(W2, fflag, W2f, F_HID * F_OUT);
    gcnx5_cvt<<<1, 64, 0, stream>>>(b2, fflag, b2f, F_OUT);

    gcnx5_deg<<<(N_EDGES + 255) / 256, 256, 0, stream>>>(ei, deg);
    gcnx5_dinv<<<(N_NODES + 255) / 256, 256, 0, stream>>>(deg, dinv);

    gcnx5_gemm1<<<N_NODES, 128, 0, stream>>>(x, fflag, W1f, h1);

    {
        long long total = (long long)N_EDGES * F_HID;
        int blocks = (int)((total + 255) / 256);
        gcnx5_agg1<<<blocks, 256, 0, stream>>>(ei, dinv, h1, agg1);
    }

    gcnx5_gemm2<<<N_NODES, 64, 0, stream>>>(agg1, h1, dinv, b1f, W2f, h2);

    {
        long long total = (long long)N_EDGES * F_OUT;
        int blocks = (int)((total + 255) / 256);
        gcnx5_agg2<<<blocks, 256, 0, stream>>>(ei, dinv, h2, agg2);
    }

    gcnx5_final<<<(N_NODES * F_OUT + 255) / 256, 256, 0, stream>>>(agg2, h2, dinv, b2f, fflag, d_out);
}